// Round 1
// baseline (3615.615 us; speedup 1.0000x reference)
//
#include <hip/hip_runtime.h>

#define NROWS 131072   // 32*64*64
#define NC 256
#define EPSV 0.001f

// ---------------- covariance accumulation ----------------
// grid 256 x 1024 threads; each block accumulates 512 rows into S (lower tri)
// and channel sums. 8x8 register tile per thread, 16-row LDS chunks.
__global__ __launch_bounds__(1024) void cov_accum_kernel(
    const float* __restrict__ x, float* __restrict__ S, float* __restrict__ sums)
{
    __shared__ float tile[16][NC];
    const int tid = threadIdx.x;
    const int ty = tid >> 5;      // 0..31 -> rows i = 8*ty..
    const int tx = tid & 31;      // 0..31 -> cols j = 4*tx+{0..3} and 128+4*tx+{0..3}
    const int i0 = ty * 8;

    float acc[8][8];
#pragma unroll
    for (int u = 0; u < 8; ++u)
#pragma unroll
        for (int v = 0; v < 8; ++v) acc[u][v] = 0.f;

    float csum = 0.f;
    const int row_base = blockIdx.x * 512;
    const int sr = tid >> 6;           // staging row 0..15
    const int sc = (tid & 63) << 2;    // staging col (float4)

    for (int ch = 0; ch < 32; ++ch) {
        const int r0 = row_base + ch * 16;
        float4 v4 = *reinterpret_cast<const float4*>(&x[(size_t)(r0 + sr) * NC + sc]);
        *reinterpret_cast<float4*>(&tile[sr][sc]) = v4;
        __syncthreads();
        if (tid < NC) {
            float s = 0.f;
#pragma unroll
            for (int r = 0; r < 16; ++r) s += tile[r][tid];
            csum += s;
        }
#pragma unroll 2
        for (int r = 0; r < 16; ++r) {
            float4 a0 = *reinterpret_cast<const float4*>(&tile[r][i0]);
            float4 a1 = *reinterpret_cast<const float4*>(&tile[r][i0 + 4]);
            float4 b0 = *reinterpret_cast<const float4*>(&tile[r][tx * 4]);
            float4 b1 = *reinterpret_cast<const float4*>(&tile[r][tx * 4 + 128]);
            float ai[8] = {a0.x, a0.y, a0.z, a0.w, a1.x, a1.y, a1.z, a1.w};
            float bj[8] = {b0.x, b0.y, b0.z, b0.w, b1.x, b1.y, b1.z, b1.w};
#pragma unroll
            for (int u = 0; u < 8; ++u)
#pragma unroll
                for (int v = 0; v < 8; ++v)
                    acc[u][v] = fmaf(ai[u], bj[v], acc[u][v]);
        }
        __syncthreads();
    }

#pragma unroll
    for (int u = 0; u < 8; ++u) {
        const int i = i0 + u;
#pragma unroll
        for (int v = 0; v < 8; ++v) {
            const int j = tx * 4 + (v & 3) + ((v < 4) ? 0 : 128);
            if (i >= j) atomicAdd(&S[i * NC + j], acc[u][v]);
        }
    }
    if (tid < NC) atomicAdd(&sums[tid], csum);
}

// ---------------- finalize covariance ----------------
__global__ void finalize_cov_kernel(const float* __restrict__ S,
                                    const float* __restrict__ sums,
                                    float* __restrict__ A)
{
    const int i = blockIdx.x;
    const int j = threadIdx.x;
    const float n = (float)NROWS;
    const float sv = (i >= j) ? S[i * NC + j] : S[j * NC + i];
    float c = (sv - sums[i] * sums[j] / n) / (n - 1.f);
    c *= (1.f - EPSV);
    if (i == j) c += EPSV;
    A[i * NC + j] = c;
}

// ---------------- Cholesky (single block, register-resident) ----------------
__global__ __launch_bounds__(1024) void chol_kernel(float* __restrict__ A)
{
    const int tid = threadIdx.x;
    const int ty = tid >> 5, tx = tid & 31;
    __shared__ float colbuf[NC];
    __shared__ float diag;
    float a[8][8];
#pragma unroll
    for (int u = 0; u < 8; ++u) {
        const int i = 8 * ty + u;
        float4 p0 = *reinterpret_cast<const float4*>(&A[i * NC + 4 * tx]);
        float4 p1 = *reinterpret_cast<const float4*>(&A[i * NC + 4 * tx + 128]);
        a[u][0] = p0.x; a[u][1] = p0.y; a[u][2] = p0.z; a[u][3] = p0.w;
        a[u][4] = p1.x; a[u][5] = p1.y; a[u][6] = p1.z; a[u][7] = p1.w;
    }
    for (int k = 0; k < NC; ++k) {
        const int txk = (k & 127) >> 2;
        const int vk = (k & 3) + ((k & 128) ? 4 : 0);
        const int tyk = k >> 3, uk = k & 7;
        if (ty == tyk && tx == txk) diag = a[uk][vk];
        __syncthreads();
        const float ld = sqrtf(diag);
        const float inv = 1.f / ld;
        if (tx == txk) {
#pragma unroll
            for (int u = 0; u < 8; ++u) {
                const int i = 8 * ty + u;
                const float val = (i == k) ? ld : a[u][vk] * inv;
                if (i >= k) { a[u][vk] = val; A[i * NC + k] = val; }
                colbuf[i] = (i <= k) ? 0.f : val;
            }
        }
        __syncthreads();
        if (8 * ty + 7 > k) {
            float4 c0 = *reinterpret_cast<const float4*>(&colbuf[8 * ty]);
            float4 c1 = *reinterpret_cast<const float4*>(&colbuf[8 * ty + 4]);
            float4 d0 = *reinterpret_cast<const float4*>(&colbuf[4 * tx]);
            float4 d1 = *reinterpret_cast<const float4*>(&colbuf[4 * tx + 128]);
            float ci[8] = {c0.x, c0.y, c0.z, c0.w, c1.x, c1.y, c1.z, c1.w};
            float cj[8] = {d0.x, d0.y, d0.z, d0.w, d1.x, d1.y, d1.z, d1.w};
#pragma unroll
            for (int u = 0; u < 8; ++u)
#pragma unroll
                for (int v = 0; v < 8; ++v)
                    a[u][v] = fmaf(-ci[u], cj[v], a[u][v]);
        }
    }
}

// ---------------- triangular inverse: W = L^{-1} ----------------
// one wave per column; solution vector distributed across lanes (wreg).
__global__ __launch_bounds__(256) void trinv_kernel(const float* __restrict__ L,
                                                    float* __restrict__ W)
{
    const int lane = threadIdx.x & 63;
    const int wv = threadIdx.x >> 6;
    const int j = blockIdx.x * 4 + wv;
    float wreg[4] = {0.f, 0.f, 0.f, 0.f};
    if (lane == 0) wreg[0] = 1.f / L[j * NC + j];
    for (int i = j + 1; i < NC; ++i) {
        float s = 0.f;
#pragma unroll
        for (int c = 0; c < 4; ++c) {
            const int t = j + lane + 64 * c;
            if (t < i) s += L[i * NC + t] * wreg[c];
        }
#pragma unroll
        for (int off = 32; off > 0; off >>= 1) s += __shfl_xor(s, off);
        const float wi = -s / L[i * NC + i];
        const int d = i - j;
        if (lane == (d & 63)) wreg[d >> 6] = wi;
    }
#pragma unroll
    for (int c = 0; c < 4; ++c) {
        const int t = j + lane + 64 * c;
        if (t < NC) W[t * NC + j] = wreg[c];
    }
}

// ---------------- whiten: out = (X - m) @ W^T ----------------
// grid (1024, 2) x 256 threads; 128x128 tile, K chunks of 32, LDS stride 44.
#define WST 44
__global__ __launch_bounds__(256) void whiten_kernel(
    const float* __restrict__ x, const float* __restrict__ W,
    const float* __restrict__ sums, float* __restrict__ out)
{
    __shared__ float Xt[128 * WST];
    __shared__ float Wt[128 * WST];
    __shared__ float mbuf[NC];
    const int tid = threadIdx.x;
    const int ty = tid >> 4, tx = tid & 15;
    const int row0 = blockIdx.x * 128;
    const int col0 = blockIdx.y * 128;
    mbuf[tid] = sums[tid] * (1.f / (float)NROWS);
    __syncthreads();

    float acc[8][8];
#pragma unroll
    for (int u = 0; u < 8; ++u)
#pragma unroll
        for (int v = 0; v < 8; ++v) acc[u][v] = 0.f;

    for (int k0 = 0; k0 < NC; k0 += 32) {
#pragma unroll
        for (int it = 0; it < 4; ++it) {
            const int idx = tid + 256 * it;
            const int rr = idx >> 3;
            const int kb = (idx & 7) << 2;
            float4 xv = *reinterpret_cast<const float4*>(&x[(size_t)(row0 + rr) * NC + k0 + kb]);
            float4 mv = *reinterpret_cast<const float4*>(&mbuf[k0 + kb]);
            xv.x -= mv.x; xv.y -= mv.y; xv.z -= mv.z; xv.w -= mv.w;
            *reinterpret_cast<float4*>(&Xt[rr * WST + kb]) = xv;
            float4 wv = *reinterpret_cast<const float4*>(&W[(size_t)(col0 + rr) * NC + k0 + kb]);
            *reinterpret_cast<float4*>(&Wt[rr * WST + kb]) = wv;
        }
        __syncthreads();
#pragma unroll
        for (int kb = 0; kb < 32; kb += 4) {
            float4 xi[8], xj[8];
#pragma unroll
            for (int u = 0; u < 8; ++u)
                xi[u] = *reinterpret_cast<const float4*>(&Xt[(8 * ty + u) * WST + kb]);
#pragma unroll
            for (int v = 0; v < 8; ++v) {
                const int jc = 4 * tx + (v & 3) + ((v < 4) ? 0 : 64);
                xj[v] = *reinterpret_cast<const float4*>(&Wt[jc * WST + kb]);
            }
#pragma unroll
            for (int u = 0; u < 8; ++u)
#pragma unroll
                for (int v = 0; v < 8; ++v) {
                    acc[u][v] = fmaf(xi[u].x, xj[v].x, acc[u][v]);
                    acc[u][v] = fmaf(xi[u].y, xj[v].y, acc[u][v]);
                    acc[u][v] = fmaf(xi[u].z, xj[v].z, acc[u][v]);
                    acc[u][v] = fmaf(xi[u].w, xj[v].w, acc[u][v]);
                }
        }
        __syncthreads();
    }
#pragma unroll
    for (int u = 0; u < 8; ++u) {
        const int i = row0 + 8 * ty + u;
#pragma unroll
        for (int q = 0; q < 2; ++q) {
            float4 o;
            o.x = acc[u][4 * q + 0]; o.y = acc[u][4 * q + 1];
            o.z = acc[u][4 * q + 2]; o.w = acc[u][4 * q + 3];
            *reinterpret_cast<float4*>(&out[(size_t)i * NC + col0 + 4 * tx + 64 * q]) = o;
        }
    }
}

extern "C" void kernel_launch(void* const* d_in, const int* in_sizes, int n_in,
                              void* d_out, int out_size, void* d_ws, size_t ws_size,
                              hipStream_t stream)
{
    const float* x = (const float*)d_in[0];
    float* out = (float*)d_out;
    float* S    = (float*)d_ws;        // 65536
    float* sums = S + 65536;           // 256
    float* A    = sums + 256;          // 65536 (cov in, L out)
    float* W    = A + 65536;           // 65536 (L^{-1})

    hipMemsetAsync(S, 0, (65536 + 256) * sizeof(float), stream);
    hipMemsetAsync(W, 0, 65536 * sizeof(float), stream);

    cov_accum_kernel<<<256, 1024, 0, stream>>>(x, S, sums);
    finalize_cov_kernel<<<256, 256, 0, stream>>>(S, sums, A);
    chol_kernel<<<1, 1024, 0, stream>>>(A);
    trinv_kernel<<<64, 256, 0, stream>>>(A, W);
    whiten_kernel<<<dim3(1024, 2), 256, 0, stream>>>(x, W, sums, out);
}

// Round 2
// 1669.340 us; speedup vs baseline: 2.1659x; 2.1659x over previous
//
#include <hip/hip_runtime.h>

#define NROWS 131072   // 32*64*64
#define NC 256
#define EPSV 0.001f

// ---------------- covariance accumulation ----------------
// grid 256 x 1024 threads; each block accumulates 512 rows into S (lower tri)
// and channel sums. 8x8 register tile per thread, 16-row LDS chunks.
__global__ __launch_bounds__(1024) void cov_accum_kernel(
    const float* __restrict__ x, float* __restrict__ S, float* __restrict__ sums)
{
    __shared__ float tile[16][NC];
    const int tid = threadIdx.x;
    const int ty = tid >> 5;      // 0..31 -> rows i = 8*ty..
    const int tx = tid & 31;      // 0..31 -> cols j = 4*tx+{0..3} and 128+4*tx+{0..3}
    const int i0 = ty * 8;

    float acc[8][8];
#pragma unroll
    for (int u = 0; u < 8; ++u)
#pragma unroll
        for (int v = 0; v < 8; ++v) acc[u][v] = 0.f;

    float csum = 0.f;
    const int row_base = blockIdx.x * 512;
    const int sr = tid >> 6;           // staging row 0..15
    const int sc = (tid & 63) << 2;    // staging col (float4)

    for (int ch = 0; ch < 32; ++ch) {
        const int r0 = row_base + ch * 16;
        float4 v4 = *reinterpret_cast<const float4*>(&x[(size_t)(r0 + sr) * NC + sc]);
        *reinterpret_cast<float4*>(&tile[sr][sc]) = v4;
        __syncthreads();
        if (tid < NC) {
            float s = 0.f;
#pragma unroll
            for (int r = 0; r < 16; ++r) s += tile[r][tid];
            csum += s;
        }
#pragma unroll 2
        for (int r = 0; r < 16; ++r) {
            float4 a0 = *reinterpret_cast<const float4*>(&tile[r][i0]);
            float4 a1 = *reinterpret_cast<const float4*>(&tile[r][i0 + 4]);
            float4 b0 = *reinterpret_cast<const float4*>(&tile[r][tx * 4]);
            float4 b1 = *reinterpret_cast<const float4*>(&tile[r][tx * 4 + 128]);
            float ai[8] = {a0.x, a0.y, a0.z, a0.w, a1.x, a1.y, a1.z, a1.w};
            float bj[8] = {b0.x, b0.y, b0.z, b0.w, b1.x, b1.y, b1.z, b1.w};
#pragma unroll
            for (int u = 0; u < 8; ++u)
#pragma unroll
                for (int v = 0; v < 8; ++v)
                    acc[u][v] = fmaf(ai[u], bj[v], acc[u][v]);
        }
        __syncthreads();
    }

#pragma unroll
    for (int u = 0; u < 8; ++u) {
        const int i = i0 + u;
#pragma unroll
        for (int v = 0; v < 8; ++v) {
            const int j = tx * 4 + (v & 3) + ((v < 4) ? 0 : 128);
            if (i >= j) atomicAdd(&S[i * NC + j], acc[u][v]);
        }
    }
    if (tid < NC) atomicAdd(&sums[tid], csum);
}

// ---------------- finalize covariance ----------------
__global__ void finalize_cov_kernel(const float* __restrict__ S,
                                    const float* __restrict__ sums,
                                    float* __restrict__ A)
{
    const int i = blockIdx.x;
    const int j = threadIdx.x;
    const float n = (float)NROWS;
    const float sv = (i >= j) ? S[i * NC + j] : S[j * NC + i];
    float c = (sv - sums[i] * sums[j] / n) / (n - 1.f);
    c *= (1.f - EPSV);
    if (i == j) c += EPSV;
    A[i * NC + j] = c;
}

// ---------------- Cholesky (single block, register-resident) ----------------
// R1 fix: ALL register-tile accesses are compile-time indexed (rule #20 —
// runtime-indexed arrays spill to scratch; R0 showed VGPR_Count=36 and
// 2560us from exactly that). Dynamic column selection is done via unrolled
// loops guarded by wave-uniform `v == vk` compares -> scalar branches.
__global__ __launch_bounds__(1024) void chol_kernel(float* __restrict__ A)
{
    const int tid = threadIdx.x;
    const int ty = tid >> 5, tx = tid & 31;
    __shared__ float colbuf[NC];
    __shared__ float diag;
    float a[8][8];
#pragma unroll
    for (int u = 0; u < 8; ++u) {
        const int i = 8 * ty + u;
        float4 p0 = *reinterpret_cast<const float4*>(&A[i * NC + 4 * tx]);
        float4 p1 = *reinterpret_cast<const float4*>(&A[i * NC + 4 * tx + 128]);
        a[u][0] = p0.x; a[u][1] = p0.y; a[u][2] = p0.z; a[u][3] = p0.w;
        a[u][4] = p1.x; a[u][5] = p1.y; a[u][6] = p1.z; a[u][7] = p1.w;
    }
    for (int k = 0; k < NC; ++k) {
        const int txk = (k & 127) >> 2;              // owning tx of column k
        const int vk = (k & 3) + ((k & 128) ? 4 : 0); // owning v-slot (uniform)
        const int tyk = k >> 3, uk = k & 7;          // owning ty / u-slot (uniform)
        if (ty == tyk && tx == txk) {
#pragma unroll
            for (int u = 0; u < 8; ++u)
#pragma unroll
                for (int v = 0; v < 8; ++v)
                    if (u == uk && v == vk) diag = a[u][v];   // static a[u][v]
        }
        __syncthreads();
        const float ld = sqrtf(diag);
        const float inv = 1.f / ld;
        if (tx == txk) {
#pragma unroll
            for (int v = 0; v < 8; ++v) {
                if (v == vk) {                                // uniform -> scalar branch
#pragma unroll
                    for (int u = 0; u < 8; ++u) {
                        const int i = 8 * ty + u;
                        const float val = (i == k) ? ld : a[u][v] * inv;
                        if (i >= k) { a[u][v] = val; A[i * NC + k] = val; }
                        colbuf[i] = (i <= k) ? 0.f : val;
                    }
                }
            }
        }
        __syncthreads();
        if (8 * ty + 7 > k) {
            float4 c0 = *reinterpret_cast<const float4*>(&colbuf[8 * ty]);
            float4 c1 = *reinterpret_cast<const float4*>(&colbuf[8 * ty + 4]);
            float4 d0 = *reinterpret_cast<const float4*>(&colbuf[4 * tx]);
            float4 d1 = *reinterpret_cast<const float4*>(&colbuf[4 * tx + 128]);
            float ci[8] = {c0.x, c0.y, c0.z, c0.w, c1.x, c1.y, c1.z, c1.w};
            float cj[8] = {d0.x, d0.y, d0.z, d0.w, d1.x, d1.y, d1.z, d1.w};
#pragma unroll
            for (int u = 0; u < 8; ++u)
#pragma unroll
                for (int v = 0; v < 8; ++v)
                    a[u][v] = fmaf(-ci[u], cj[v], a[u][v]);
        }
    }
}

// ---------------- triangular inverse: W = L^{-1} ----------------
// one wave per column; solution vector distributed across lanes (wreg).
__global__ __launch_bounds__(256) void trinv_kernel(const float* __restrict__ L,
                                                    float* __restrict__ W)
{
    const int lane = threadIdx.x & 63;
    const int wv = threadIdx.x >> 6;
    const int j = blockIdx.x * 4 + wv;
    float wreg[4] = {0.f, 0.f, 0.f, 0.f};
    if (lane == 0) wreg[0] = 1.f / L[j * NC + j];
    for (int i = j + 1; i < NC; ++i) {
        float s = 0.f;
#pragma unroll
        for (int c = 0; c < 4; ++c) {
            const int t = j + lane + 64 * c;
            if (t < i) s += L[i * NC + t] * wreg[c];
        }
#pragma unroll
        for (int off = 32; off > 0; off >>= 1) s += __shfl_xor(s, off);
        const float wi = -s / L[i * NC + i];
        const int d = i - j;
        if (lane == (d & 63)) wreg[d >> 6] = wi;
    }
#pragma unroll
    for (int c = 0; c < 4; ++c) {
        const int t = j + lane + 64 * c;
        if (t < NC) W[t * NC + j] = wreg[c];
    }
}

// ---------------- whiten: out = (X - m) @ W^T ----------------
// grid (1024, 2) x 256 threads; 128x128 tile, K chunks of 32, LDS stride 44.
#define WST 44
__global__ __launch_bounds__(256) void whiten_kernel(
    const float* __restrict__ x, const float* __restrict__ W,
    const float* __restrict__ sums, float* __restrict__ out)
{
    __shared__ float Xt[128 * WST];
    __shared__ float Wt[128 * WST];
    __shared__ float mbuf[NC];
    const int tid = threadIdx.x;
    const int ty = tid >> 4, tx = tid & 15;
    const int row0 = blockIdx.x * 128;
    const int col0 = blockIdx.y * 128;
    mbuf[tid] = sums[tid] * (1.f / (float)NROWS);
    __syncthreads();

    float acc[8][8];
#pragma unroll
    for (int u = 0; u < 8; ++u)
#pragma unroll
        for (int v = 0; v < 8; ++v) acc[u][v] = 0.f;

    for (int k0 = 0; k0 < NC; k0 += 32) {
#pragma unroll
        for (int it = 0; it < 4; ++it) {
            const int idx = tid + 256 * it;
            const int rr = idx >> 3;
            const int kb = (idx & 7) << 2;
            float4 xv = *reinterpret_cast<const float4*>(&x[(size_t)(row0 + rr) * NC + k0 + kb]);
            float4 mv = *reinterpret_cast<const float4*>(&mbuf[k0 + kb]);
            xv.x -= mv.x; xv.y -= mv.y; xv.z -= mv.z; xv.w -= mv.w;
            *reinterpret_cast<float4*>(&Xt[rr * WST + kb]) = xv;
            float4 wv = *reinterpret_cast<const float4*>(&W[(size_t)(col0 + rr) * NC + k0 + kb]);
            *reinterpret_cast<float4*>(&Wt[rr * WST + kb]) = wv;
        }
        __syncthreads();
#pragma unroll
        for (int kb = 0; kb < 32; kb += 4) {
            float4 xi[8], xj[8];
#pragma unroll
            for (int u = 0; u < 8; ++u)
                xi[u] = *reinterpret_cast<const float4*>(&Xt[(8 * ty + u) * WST + kb]);
#pragma unroll
            for (int v = 0; v < 8; ++v) {
                const int jc = 4 * tx + (v & 3) + ((v < 4) ? 0 : 64);
                xj[v] = *reinterpret_cast<const float4*>(&Wt[jc * WST + kb]);
            }
#pragma unroll
            for (int u = 0; u < 8; ++u)
#pragma unroll
                for (int v = 0; v < 8; ++v) {
                    acc[u][v] = fmaf(xi[u].x, xj[v].x, acc[u][v]);
                    acc[u][v] = fmaf(xi[u].y, xj[v].y, acc[u][v]);
                    acc[u][v] = fmaf(xi[u].z, xj[v].z, acc[u][v]);
                    acc[u][v] = fmaf(xi[u].w, xj[v].w, acc[u][v]);
                }
        }
        __syncthreads();
    }
#pragma unroll
    for (int u = 0; u < 8; ++u) {
        const int i = row0 + 8 * ty + u;
#pragma unroll
        for (int q = 0; q < 2; ++q) {
            float4 o;
            o.x = acc[u][4 * q + 0]; o.y = acc[u][4 * q + 1];
            o.z = acc[u][4 * q + 2]; o.w = acc[u][4 * q + 3];
            *reinterpret_cast<float4*>(&out[(size_t)i * NC + col0 + 4 * tx + 64 * q]) = o;
        }
    }
}

extern "C" void kernel_launch(void* const* d_in, const int* in_sizes, int n_in,
                              void* d_out, int out_size, void* d_ws, size_t ws_size,
                              hipStream_t stream)
{
    const float* x = (const float*)d_in[0];
    float* out = (float*)d_out;
    float* S    = (float*)d_ws;        // 65536
    float* sums = S + 65536;           // 256
    float* A    = sums + 256;          // 65536 (cov in, L out)
    float* W    = A + 65536;           // 65536 (L^{-1})

    hipMemsetAsync(S, 0, (65536 + 256) * sizeof(float), stream);
    hipMemsetAsync(W, 0, 65536 * sizeof(float), stream);

    cov_accum_kernel<<<256, 1024, 0, stream>>>(x, S, sums);
    finalize_cov_kernel<<<256, 256, 0, stream>>>(S, sums, A);
    chol_kernel<<<1, 1024, 0, stream>>>(A);
    trinv_kernel<<<64, 256, 0, stream>>>(A, W);
    whiten_kernel<<<dim3(1024, 2), 256, 0, stream>>>(x, W, sums, out);
}

// Round 4
// 1589.261 us; speedup vs baseline: 2.2750x; 1.0504x over previous
//
#include <hip/hip_runtime.h>

#define NROWS 131072   // 32*64*64
#define NC 256
#define EPSV 0.001f

// ---------------- covariance accumulation ----------------
// grid 256 x 1024 threads; each block accumulates 512 rows into S (lower tri)
// and channel sums. 8x8 register tile per thread, 16-row LDS chunks.
// __launch_bounds__(1024,4): single 1024-thr block = 16 waves = 4/EU; declaring
// 4 waves/EU gives the 128-VGPR budget the 64-float acc tile needs (R1->R2:
// default budget spilled the tile, VGPR_Count=52).
__global__ __launch_bounds__(1024, 4) void cov_accum_kernel(
    const float* __restrict__ x, float* __restrict__ S, float* __restrict__ sums)
{
    __shared__ float tile[16][NC];
    const int tid = threadIdx.x;
    const int ty = tid >> 5;      // 0..31 -> rows i = 8*ty..
    const int tx = tid & 31;      // 0..31 -> cols j = 4*tx+{0..3} and 128+4*tx+{0..3}
    const int i0 = ty * 8;

    float acc[8][8];
#pragma unroll
    for (int u = 0; u < 8; ++u)
#pragma unroll
        for (int v = 0; v < 8; ++v) acc[u][v] = 0.f;

    float csum = 0.f;
    const int row_base = blockIdx.x * 512;
    const int sr = tid >> 6;           // staging row 0..15
    const int sc = (tid & 63) << 2;    // staging col (float4)

    for (int ch = 0; ch < 32; ++ch) {
        const int r0 = row_base + ch * 16;
        float4 v4 = *reinterpret_cast<const float4*>(&x[(size_t)(r0 + sr) * NC + sc]);
        *reinterpret_cast<float4*>(&tile[sr][sc]) = v4;
        __syncthreads();
        if (tid < NC) {
            float s = 0.f;
#pragma unroll
            for (int r = 0; r < 16; ++r) s += tile[r][tid];
            csum += s;
        }
#pragma unroll 2
        for (int r = 0; r < 16; ++r) {
            float4 a0 = *reinterpret_cast<const float4*>(&tile[r][i0]);
            float4 a1 = *reinterpret_cast<const float4*>(&tile[r][i0 + 4]);
            float4 b0 = *reinterpret_cast<const float4*>(&tile[r][tx * 4]);
            float4 b1 = *reinterpret_cast<const float4*>(&tile[r][tx * 4 + 128]);
            float ai[8] = {a0.x, a0.y, a0.z, a0.w, a1.x, a1.y, a1.z, a1.w};
            float bj[8] = {b0.x, b0.y, b0.z, b0.w, b1.x, b1.y, b1.z, b1.w};
#pragma unroll
            for (int u = 0; u < 8; ++u)
#pragma unroll
                for (int v = 0; v < 8; ++v)
                    acc[u][v] = fmaf(ai[u], bj[v], acc[u][v]);
        }
        __syncthreads();
    }

#pragma unroll
    for (int u = 0; u < 8; ++u) {
        const int i = i0 + u;
#pragma unroll
        for (int v = 0; v < 8; ++v) {
            const int j = tx * 4 + (v & 3) + ((v < 4) ? 0 : 128);
            if (i >= j) atomicAdd(&S[i * NC + j], acc[u][v]);
        }
    }
    if (tid < NC) atomicAdd(&sums[tid], csum);
}

// ---------------- finalize covariance ----------------
__global__ void finalize_cov_kernel(const float* __restrict__ S,
                                    const float* __restrict__ sums,
                                    float* __restrict__ A)
{
    const int i = blockIdx.x;
    const int j = threadIdx.x;
    const float n = (float)NROWS;
    const float sv = (i >= j) ? S[i * NC + j] : S[j * NC + i];
    float c = (sv - sums[i] * sums[j] / n) / (n - 1.f);
    c *= (1.f - EPSV);
    if (i == j) c += EPSV;
    A[i * NC + j] = c;
}

// ---------------- Cholesky (single block, register-resident) ----------------
// R2 structure: ONE barrier per column. colbuf (double-buffered, diag in slot
// [NC]) always holds the UNSCALED post-update next column, staged by that
// column's owner before the barrier. All threads derive 1/diag and fold the
// scaling into the rank-1 update; colbuf entries i<=k are zeroed so the
// update self-masks (no guards, no second barrier, no diag-extraction scan).
// __launch_bounds__(1024,4): 128-VGPR budget so the 64-float tile stays
// register-resident (R1: default budget spilled it at VGPR=52).
__global__ __launch_bounds__(1024, 4) void chol_kernel(float* __restrict__ A)
{
    const int tid = threadIdx.x;
    const int ty = tid >> 5, tx = tid & 31;
    __shared__ float colbuf[2][NC + 1];    // [.][NC] = diag slot
    float a[8][8];
#pragma unroll
    for (int u = 0; u < 8; ++u) {
        const int i = 8 * ty + u;
        float4 p0 = *reinterpret_cast<const float4*>(&A[i * NC + 4 * tx]);
        float4 p1 = *reinterpret_cast<const float4*>(&A[i * NC + 4 * tx + 128]);
        a[u][0] = p0.x; a[u][1] = p0.y; a[u][2] = p0.z; a[u][3] = p0.w;
        a[u][4] = p1.x; a[u][5] = p1.y; a[u][6] = p1.z; a[u][7] = p1.w;
    }
    // seed: stage column 0 (owner tx==0, v-slot 0)
    if (tx == 0) {
#pragma unroll
        for (int u = 0; u < 8; ++u) {
            const int i = 8 * ty + u;
            colbuf[0][i] = (i == 0) ? 0.f : a[u][0];
            if (i == 0) colbuf[0][NC] = a[u][0];
        }
    }
    __syncthreads();

    for (int k = 0; k < NC; ++k) {
        const int b = k & 1;
        const float diag = colbuf[b][NC];
        const float ld = sqrtf(diag);
        const float inv = 1.f / ld;
        const float rd = inv * inv;

        float4 c0 = *reinterpret_cast<const float4*>(&colbuf[b][8 * ty]);
        float4 c1 = *reinterpret_cast<const float4*>(&colbuf[b][8 * ty + 4]);
        float4 d0 = *reinterpret_cast<const float4*>(&colbuf[b][4 * tx]);
        float4 d1 = *reinterpret_cast<const float4*>(&colbuf[b][4 * tx + 128]);
        float ci[8] = {c0.x, c0.y, c0.z, c0.w, c1.x, c1.y, c1.z, c1.w};
        float cj[8] = {d0.x, d0.y, d0.z, d0.w, d1.x, d1.y, d1.z, d1.w};

        float cir[8];
#pragma unroll
        for (int u = 0; u < 8; ++u) cir[u] = ci[u] * rd;
        // rank-1 update; rows/cols <= k have c==0 -> no-op (incl. column k itself)
#pragma unroll
        for (int u = 0; u < 8; ++u)
#pragma unroll
            for (int v = 0; v < 8; ++v)
                a[u][v] = fmaf(-cir[u], cj[v], a[u][v]);

        // owner scales column k in-register and writes L to global
        const int txk = (k & 127) >> 2;
        const int vk = (k & 3) + ((k & 128) ? 4 : 0);
        if (tx == txk) {
#pragma unroll
            for (int v = 0; v < 8; ++v) {
                if (v == vk) {   // wave-uniform -> scalar branch; static a[u][v]
#pragma unroll
                    for (int u = 0; u < 8; ++u) {
                        const int i = 8 * ty + u;
                        if (i >= k) {
                            const float val = (i == k) ? ld : a[u][v] * inv;
                            a[u][v] = val;
                            A[i * NC + k] = val;
                        }
                    }
                }
            }
        }
        // stage next column (unscaled, post-update) into the other buffer
        const int kn = k + 1;
        if (kn < NC) {
            const int txn = (kn & 127) >> 2;
            const int vn = (kn & 3) + ((kn & 128) ? 4 : 0);
            if (tx == txn) {
#pragma unroll
                for (int v = 0; v < 8; ++v) {
                    if (v == vn) {
#pragma unroll
                        for (int u = 0; u < 8; ++u) {
                            const int i = 8 * ty + u;
                            colbuf[b ^ 1][i] = (i <= kn) ? 0.f : a[u][v];
                            if (i == kn) colbuf[b ^ 1][NC] = a[u][v];
                        }
                    }
                }
            }
        }
        __syncthreads();
    }
}

// ---------------- triangular inverse: W = L^{-1} ----------------
// one wave per column; solution vector distributed across lanes (wreg).
__global__ __launch_bounds__(256) void trinv_kernel(const float* __restrict__ L,
                                                    float* __restrict__ W)
{
    const int lane = threadIdx.x & 63;
    const int wv = threadIdx.x >> 6;
    const int j = blockIdx.x * 4 + wv;
    float wreg[4] = {0.f, 0.f, 0.f, 0.f};
    if (lane == 0) wreg[0] = 1.f / L[j * NC + j];
    for (int i = j + 1; i < NC; ++i) {
        float s = 0.f;
#pragma unroll
        for (int c = 0; c < 4; ++c) {
            const int t = j + lane + 64 * c;
            if (t < i) s += L[i * NC + t] * wreg[c];
        }
#pragma unroll
        for (int off = 32; off > 0; off >>= 1) s += __shfl_xor(s, off);
        const float wi = -s / L[i * NC + i];
        const int d = i - j;
        if (lane == (d & 63)) wreg[d >> 6] = wi;
    }
#pragma unroll
    for (int c = 0; c < 4; ++c) {
        const int t = j + lane + 64 * c;
        if (t < NC) W[t * NC + j] = wreg[c];
    }
}

// ---------------- whiten: out = (X - m) @ W^T ----------------
// grid (1024, 2) x 256 threads; 128x128 tile, K chunks of 32, LDS stride 44.
#define WST 44
__global__ __launch_bounds__(256) void whiten_kernel(
    const float* __restrict__ x, const float* __restrict__ W,
    const float* __restrict__ sums, float* __restrict__ out)
{
    __shared__ float Xt[128 * WST];
    __shared__ float Wt[128 * WST];
    __shared__ float mbuf[NC];
    const int tid = threadIdx.x;
    const int ty = tid >> 4, tx = tid & 15;
    const int row0 = blockIdx.x * 128;
    const int col0 = blockIdx.y * 128;
    mbuf[tid] = sums[tid] * (1.f / (float)NROWS);
    __syncthreads();

    float acc[8][8];
#pragma unroll
    for (int u = 0; u < 8; ++u)
#pragma unroll
        for (int v = 0; v < 8; ++v) acc[u][v] = 0.f;

    for (int k0 = 0; k0 < NC; k0 += 32) {
#pragma unroll
        for (int it = 0; it < 4; ++it) {
            const int idx = tid + 256 * it;
            const int rr = idx >> 3;
            const int kb = (idx & 7) << 2;
            float4 xv = *reinterpret_cast<const float4*>(&x[(size_t)(row0 + rr) * NC + k0 + kb]);
            float4 mv = *reinterpret_cast<const float4*>(&mbuf[k0 + kb]);
            xv.x -= mv.x; xv.y -= mv.y; xv.z -= mv.z; xv.w -= mv.w;
            *reinterpret_cast<float4*>(&Xt[rr * WST + kb]) = xv;
            float4 wv = *reinterpret_cast<const float4*>(&W[(size_t)(col0 + rr) * NC + k0 + kb]);
            *reinterpret_cast<float4*>(&Wt[rr * WST + kb]) = wv;
        }
        __syncthreads();
#pragma unroll
        for (int kb = 0; kb < 32; kb += 4) {
            float4 xi[8], xj[8];
#pragma unroll
            for (int u = 0; u < 8; ++u)
                xi[u] = *reinterpret_cast<const float4*>(&Xt[(8 * ty + u) * WST + kb]);
#pragma unroll
            for (int v = 0; v < 8; ++v) {
                const int jc = 4 * tx + (v & 3) + ((v < 4) ? 0 : 64);
                xj[v] = *reinterpret_cast<const float4*>(&Wt[jc * WST + kb]);
            }
#pragma unroll
            for (int u = 0; u < 8; ++u)
#pragma unroll
                for (int v = 0; v < 8; ++v) {
                    acc[u][v] = fmaf(xi[u].x, xj[v].x, acc[u][v]);
                    acc[u][v] = fmaf(xi[u].y, xj[v].y, acc[u][v]);
                    acc[u][v] = fmaf(xi[u].z, xj[v].z, acc[u][v]);
                    acc[u][v] = fmaf(xi[u].w, xj[v].w, acc[u][v]);
                }
        }
        __syncthreads();
    }
#pragma unroll
    for (int u = 0; u < 8; ++u) {
        const int i = row0 + 8 * ty + u;
#pragma unroll
        for (int q = 0; q < 2; ++q) {
            float4 o;
            o.x = acc[u][4 * q + 0]; o.y = acc[u][4 * q + 1];
            o.z = acc[u][4 * q + 2]; o.w = acc[u][4 * q + 3];
            *reinterpret_cast<float4*>(&out[(size_t)i * NC + col0 + 4 * tx + 64 * q]) = o;
        }
    }
}

extern "C" void kernel_launch(void* const* d_in, const int* in_sizes, int n_in,
                              void* d_out, int out_size, void* d_ws, size_t ws_size,
                              hipStream_t stream)
{
    const float* x = (const float*)d_in[0];
    float* out = (float*)d_out;
    float* S    = (float*)d_ws;        // 65536
    float* sums = S + 65536;           // 256
    float* A    = sums + 256;          // 65536 (cov in, L out)
    float* W    = A + 65536;           // 65536 (L^{-1})

    hipMemsetAsync(S, 0, (65536 + 256) * sizeof(float), stream);
    hipMemsetAsync(W, 0, 65536 * sizeof(float), stream);

    cov_accum_kernel<<<256, 1024, 0, stream>>>(x, S, sums);
    finalize_cov_kernel<<<256, 256, 0, stream>>>(S, sums, A);
    chol_kernel<<<1, 1024, 0, stream>>>(A);
    trinv_kernel<<<64, 256, 0, stream>>>(A, W);
    whiten_kernel<<<dim3(1024, 2), 256, 0, stream>>>(x, W, sums, out);
}

// Round 5
// 1516.367 us; speedup vs baseline: 2.3844x; 1.0481x over previous
//
#include <hip/hip_runtime.h>

#define NROWS 131072   // 32*64*64
#define NC 256
#define EPSV 0.001f

// ---------------- covariance accumulation ----------------
// grid 256 x 1024 threads; each block accumulates 512 rows into S (lower tri)
// and channel sums. 8x8 register tile per thread, 16-row LDS chunks.
__global__ __launch_bounds__(1024, 4) void cov_accum_kernel(
    const float* __restrict__ x, float* __restrict__ S, float* __restrict__ sums)
{
    __shared__ float tile[16][NC];
    const int tid = threadIdx.x;
    const int ty = tid >> 5;      // 0..31 -> rows i = 8*ty..
    const int tx = tid & 31;      // 0..31 -> cols j = 4*tx+{0..3} and 128+4*tx+{0..3}
    const int i0 = ty * 8;

    float acc[8][8];
#pragma unroll
    for (int u = 0; u < 8; ++u)
#pragma unroll
        for (int v = 0; v < 8; ++v) acc[u][v] = 0.f;

    float csum = 0.f;
    const int row_base = blockIdx.x * 512;
    const int sr = tid >> 6;           // staging row 0..15
    const int sc = (tid & 63) << 2;    // staging col (float4)

    for (int ch = 0; ch < 32; ++ch) {
        const int r0 = row_base + ch * 16;
        float4 v4 = *reinterpret_cast<const float4*>(&x[(size_t)(r0 + sr) * NC + sc]);
        *reinterpret_cast<float4*>(&tile[sr][sc]) = v4;
        __syncthreads();
        if (tid < NC) {
            float s = 0.f;
#pragma unroll
            for (int r = 0; r < 16; ++r) s += tile[r][tid];
            csum += s;
        }
#pragma unroll 2
        for (int r = 0; r < 16; ++r) {
            float4 a0 = *reinterpret_cast<const float4*>(&tile[r][i0]);
            float4 a1 = *reinterpret_cast<const float4*>(&tile[r][i0 + 4]);
            float4 b0 = *reinterpret_cast<const float4*>(&tile[r][tx * 4]);
            float4 b1 = *reinterpret_cast<const float4*>(&tile[r][tx * 4 + 128]);
            float ai[8] = {a0.x, a0.y, a0.z, a0.w, a1.x, a1.y, a1.z, a1.w};
            float bj[8] = {b0.x, b0.y, b0.z, b0.w, b1.x, b1.y, b1.z, b1.w};
#pragma unroll
            for (int u = 0; u < 8; ++u)
#pragma unroll
                for (int v = 0; v < 8; ++v)
                    acc[u][v] = fmaf(ai[u], bj[v], acc[u][v]);
        }
        __syncthreads();
    }

#pragma unroll
    for (int u = 0; u < 8; ++u) {
        const int i = i0 + u;
#pragma unroll
        for (int v = 0; v < 8; ++v) {
            const int j = tx * 4 + (v & 3) + ((v < 4) ? 0 : 128);
            if (i >= j) atomicAdd(&S[i * NC + j], acc[u][v]);
        }
    }
    if (tid < NC) atomicAdd(&sums[tid], csum);
}

// ---------------- finalize covariance ----------------
__global__ void finalize_cov_kernel(const float* __restrict__ S,
                                    const float* __restrict__ sums,
                                    float* __restrict__ A)
{
    const int i = blockIdx.x;
    const int j = threadIdx.x;
    const float n = (float)NROWS;
    const float sv = (i >= j) ? S[i * NC + j] : S[j * NC + i];
    float c = (sv - sums[i] * sums[j] / n) / (n - 1.f);
    c *= (1.f - EPSV);
    if (i == j) c += EPSV;
    A[i * NC + j] = c;
}

// ---------------- Cholesky (single block) ----------------
// R4: the 8x8 per-thread tile is 64 NAMED SCALARS (macro-generated), not an
// array. R1/R2 showed arrays + #pragma unroll + static guards still fail SROA
// (VGPR stuck at 52 = tile in scratch, 518us): promotion runs before full
// unrolling, so loop-variant GEPs kill it regardless of the register budget.
// Named scalars are mem2reg'd in the frontend -> promotion cannot fail.
// Column selection (wave-uniform vk) is an 8-case switch, each case static.
// Structure: ONE barrier/column; colbuf (double-buffered, diag in slot [NC])
// holds the UNSCALED post-update next column; scaling folded into the rank-1
// via rd = 1/diag; colbuf entries i<=k zeroed so the update self-masks.
#define CH_DECL(u) float a##u##_0, a##u##_1, a##u##_2, a##u##_3, a##u##_4, a##u##_5, a##u##_6, a##u##_7;
#define CH_LOAD(u) { const int i = 8 * ty + (u); \
    float4 p0 = *reinterpret_cast<const float4*>(&A[i * NC + 4 * tx]); \
    float4 p1 = *reinterpret_cast<const float4*>(&A[i * NC + 4 * tx + 128]); \
    a##u##_0 = p0.x; a##u##_1 = p0.y; a##u##_2 = p0.z; a##u##_3 = p0.w; \
    a##u##_4 = p1.x; a##u##_5 = p1.y; a##u##_6 = p1.z; a##u##_7 = p1.w; }
#define CH_SEED(u) { const int i = 8 * ty + (u); \
    colbuf[0][i] = (i == 0) ? 0.f : a##u##_0; if (i == 0) colbuf[0][NC] = a##u##_0; }
#define CH_UPD(u, ru) \
    a##u##_0 = fmaf(-(ru), d0.x, a##u##_0); a##u##_1 = fmaf(-(ru), d0.y, a##u##_1); \
    a##u##_2 = fmaf(-(ru), d0.z, a##u##_2); a##u##_3 = fmaf(-(ru), d0.w, a##u##_3); \
    a##u##_4 = fmaf(-(ru), d1.x, a##u##_4); a##u##_5 = fmaf(-(ru), d1.y, a##u##_5); \
    a##u##_6 = fmaf(-(ru), d1.z, a##u##_6); a##u##_7 = fmaf(-(ru), d1.w, a##u##_7);
#define CH_SCALE(u, v) { const int i = 8 * ty + (u); \
    if (i >= k) { const float val = (i == k) ? ld : a##u##_##v * inv; a##u##_##v = val; A[i * NC + k] = val; } }
#define CH_SCALE8(v) CH_SCALE(0, v) CH_SCALE(1, v) CH_SCALE(2, v) CH_SCALE(3, v) \
                     CH_SCALE(4, v) CH_SCALE(5, v) CH_SCALE(6, v) CH_SCALE(7, v)
#define CH_STAGE(u, v) { const int i = 8 * ty + (u); \
    colbuf[nb][i] = (i <= kn) ? 0.f : a##u##_##v; if (i == kn) colbuf[nb][NC] = a##u##_##v; }
#define CH_STAGE8(v) CH_STAGE(0, v) CH_STAGE(1, v) CH_STAGE(2, v) CH_STAGE(3, v) \
                     CH_STAGE(4, v) CH_STAGE(5, v) CH_STAGE(6, v) CH_STAGE(7, v)

__global__ __launch_bounds__(1024, 4) void chol_kernel(float* __restrict__ A)
{
    const int tid = threadIdx.x;
    const int ty = tid >> 5, tx = tid & 31;
    __shared__ float colbuf[2][NC + 1];    // [.][NC] = diag slot

    CH_DECL(0) CH_DECL(1) CH_DECL(2) CH_DECL(3)
    CH_DECL(4) CH_DECL(5) CH_DECL(6) CH_DECL(7)

    CH_LOAD(0) CH_LOAD(1) CH_LOAD(2) CH_LOAD(3)
    CH_LOAD(4) CH_LOAD(5) CH_LOAD(6) CH_LOAD(7)

    // seed: stage column 0 (owner tx==0, v-slot 0)
    if (tx == 0) {
        CH_SEED(0) CH_SEED(1) CH_SEED(2) CH_SEED(3)
        CH_SEED(4) CH_SEED(5) CH_SEED(6) CH_SEED(7)
    }
    __syncthreads();

    for (int k = 0; k < NC; ++k) {
        const int b = k & 1, nb = b ^ 1;
        const float diag = colbuf[b][NC];
        const float ld = sqrtf(diag);
        const float inv = 1.f / ld;
        const float rd = inv * inv;

        float4 c0 = *reinterpret_cast<const float4*>(&colbuf[b][8 * ty]);
        float4 c1 = *reinterpret_cast<const float4*>(&colbuf[b][8 * ty + 4]);
        float4 d0 = *reinterpret_cast<const float4*>(&colbuf[b][4 * tx]);
        float4 d1 = *reinterpret_cast<const float4*>(&colbuf[b][4 * tx + 128]);
        const float r0 = c0.x * rd, r1 = c0.y * rd, r2 = c0.z * rd, r3 = c0.w * rd;
        const float r4 = c1.x * rd, r5 = c1.y * rd, r6 = c1.z * rd, r7 = c1.w * rd;

        // rank-1 update; rows/cols <= k have colbuf==0 -> no-op
        CH_UPD(0, r0) CH_UPD(1, r1) CH_UPD(2, r2) CH_UPD(3, r3)
        CH_UPD(4, r4) CH_UPD(5, r5) CH_UPD(6, r6) CH_UPD(7, r7)

        // owner scales column k in-register and writes L to global
        const int txk = (k & 127) >> 2;
        const int vk = (k & 3) + ((k & 128) ? 4 : 0);
        if (tx == txk) {
            switch (vk) {   // wave-uniform -> scalar branch tree
                case 0: CH_SCALE8(0) break;
                case 1: CH_SCALE8(1) break;
                case 2: CH_SCALE8(2) break;
                case 3: CH_SCALE8(3) break;
                case 4: CH_SCALE8(4) break;
                case 5: CH_SCALE8(5) break;
                case 6: CH_SCALE8(6) break;
                case 7: CH_SCALE8(7) break;
            }
        }
        // stage next column (unscaled, post-update) into the other buffer
        const int kn = k + 1;
        if (kn < NC) {
            const int txn = (kn & 127) >> 2;
            const int vn = (kn & 3) + ((kn & 128) ? 4 : 0);
            if (tx == txn) {
                switch (vn) {
                    case 0: CH_STAGE8(0) break;
                    case 1: CH_STAGE8(1) break;
                    case 2: CH_STAGE8(2) break;
                    case 3: CH_STAGE8(3) break;
                    case 4: CH_STAGE8(4) break;
                    case 5: CH_STAGE8(5) break;
                    case 6: CH_STAGE8(6) break;
                    case 7: CH_STAGE8(7) break;
                }
            }
        }
        __syncthreads();
    }
}

// ---------------- triangular inverse: W = L^{-1} ----------------
// one wave per column; solution vector distributed across lanes (wreg).
__global__ __launch_bounds__(256) void trinv_kernel(const float* __restrict__ L,
                                                    float* __restrict__ W)
{
    const int lane = threadIdx.x & 63;
    const int wv = threadIdx.x >> 6;
    const int j = blockIdx.x * 4 + wv;
    float wreg[4] = {0.f, 0.f, 0.f, 0.f};
    if (lane == 0) wreg[0] = 1.f / L[j * NC + j];
    for (int i = j + 1; i < NC; ++i) {
        float s = 0.f;
#pragma unroll
        for (int c = 0; c < 4; ++c) {
            const int t = j + lane + 64 * c;
            if (t < i) s += L[i * NC + t] * wreg[c];
        }
#pragma unroll
        for (int off = 32; off > 0; off >>= 1) s += __shfl_xor(s, off);
        const float wi = -s / L[i * NC + i];
        const int d = i - j;
        if (lane == (d & 63)) wreg[d >> 6] = wi;
    }
#pragma unroll
    for (int c = 0; c < 4; ++c) {
        const int t = j + lane + 64 * c;
        if (t < NC) W[t * NC + j] = wreg[c];
    }
}

// ---------------- whiten: out = (X - m) @ W^T ----------------
// grid (1024, 2) x 256 threads; 128x128 tile, K chunks of 32, LDS stride 44.
#define WST 44
__global__ __launch_bounds__(256) void whiten_kernel(
    const float* __restrict__ x, const float* __restrict__ W,
    const float* __restrict__ sums, float* __restrict__ out)
{
    __shared__ float Xt[128 * WST];
    __shared__ float Wt[128 * WST];
    __shared__ float mbuf[NC];
    const int tid = threadIdx.x;
    const int ty = tid >> 4, tx = tid & 15;
    const int row0 = blockIdx.x * 128;
    const int col0 = blockIdx.y * 128;
    mbuf[tid] = sums[tid] * (1.f / (float)NROWS);
    __syncthreads();

    float acc[8][8];
#pragma unroll
    for (int u = 0; u < 8; ++u)
#pragma unroll
        for (int v = 0; v < 8; ++v) acc[u][v] = 0.f;

    for (int k0 = 0; k0 < NC; k0 += 32) {
#pragma unroll
        for (int it = 0; it < 4; ++it) {
            const int idx = tid + 256 * it;
            const int rr = idx >> 3;
            const int kb = (idx & 7) << 2;
            float4 xv = *reinterpret_cast<const float4*>(&x[(size_t)(row0 + rr) * NC + k0 + kb]);
            float4 mv = *reinterpret_cast<const float4*>(&mbuf[k0 + kb]);
            xv.x -= mv.x; xv.y -= mv.y; xv.z -= mv.z; xv.w -= mv.w;
            *reinterpret_cast<float4*>(&Xt[rr * WST + kb]) = xv;
            float4 wv = *reinterpret_cast<const float4*>(&W[(size_t)(col0 + rr) * NC + k0 + kb]);
            *reinterpret_cast<float4*>(&Wt[rr * WST + kb]) = wv;
        }
        __syncthreads();
#pragma unroll
        for (int kb = 0; kb < 32; kb += 4) {
            float4 xi[8], xj[8];
#pragma unroll
            for (int u = 0; u < 8; ++u)
                xi[u] = *reinterpret_cast<const float4*>(&Xt[(8 * ty + u) * WST + kb]);
#pragma unroll
            for (int v = 0; v < 8; ++v) {
                const int jc = 4 * tx + (v & 3) + ((v < 4) ? 0 : 64);
                xj[v] = *reinterpret_cast<const float4*>(&Wt[jc * WST + kb]);
            }
#pragma unroll
            for (int u = 0; u < 8; ++u)
#pragma unroll
                for (int v = 0; v < 8; ++v) {
                    acc[u][v] = fmaf(xi[u].x, xj[v].x, acc[u][v]);
                    acc[u][v] = fmaf(xi[u].y, xj[v].y, acc[u][v]);
                    acc[u][v] = fmaf(xi[u].z, xj[v].z, acc[u][v]);
                    acc[u][v] = fmaf(xi[u].w, xj[v].w, acc[u][v]);
                }
        }
        __syncthreads();
    }
#pragma unroll
    for (int u = 0; u < 8; ++u) {
        const int i = row0 + 8 * ty + u;
#pragma unroll
        for (int q = 0; q < 2; ++q) {
            float4 o;
            o.x = acc[u][4 * q + 0]; o.y = acc[u][4 * q + 1];
            o.z = acc[u][4 * q + 2]; o.w = acc[u][4 * q + 3];
            *reinterpret_cast<float4*>(&out[(size_t)i * NC + col0 + 4 * tx + 64 * q]) = o;
        }
    }
}

extern "C" void kernel_launch(void* const* d_in, const int* in_sizes, int n_in,
                              void* d_out, int out_size, void* d_ws, size_t ws_size,
                              hipStream_t stream)
{
    const float* x = (const float*)d_in[0];
    float* out = (float*)d_out;
    float* S    = (float*)d_ws;        // 65536
    float* sums = S + 65536;           // 256
    float* A    = sums + 256;          // 65536 (cov in, L out)
    float* W    = A + 65536;           // 65536 (L^{-1})

    hipMemsetAsync(S, 0, (65536 + 256) * sizeof(float), stream);
    hipMemsetAsync(W, 0, 65536 * sizeof(float), stream);

    cov_accum_kernel<<<256, 1024, 0, stream>>>(x, S, sums);
    finalize_cov_kernel<<<256, 256, 0, stream>>>(S, sums, A);
    chol_kernel<<<1, 1024, 0, stream>>>(A);
    trinv_kernel<<<64, 256, 0, stream>>>(A, W);
    whiten_kernel<<<dim3(1024, 2), 256, 0, stream>>>(x, W, sums, out);
}